// Round 12
// baseline (121.285 us; speedup 1.0000x reference)
//
#include <hip/hip_runtime.h>
#include <hip/hip_bf16.h>

#define CS 384
#define CH 32
#define CZ 128
#define LL 384
#define NL 1536   // N*L
#define EPS 1e-5f

typedef float v4f __attribute__((ext_vector_type(4)));
typedef short s8v __attribute__((ext_vector_type(8)));          // 8 bf16 (MFMA A/B frag)
typedef unsigned short u8s __attribute__((ext_vector_type(8))); // 8 bf16 bits

static __device__ __forceinline__ unsigned short f2bf(float x) {
    unsigned int b = __float_as_uint(x);
    b += 0x7FFFu + ((b >> 16) & 1u);        // round-to-nearest-even
    return (unsigned short)(b >> 16);
}

// ---------------- Kernel 1: fused LN + A,B matvec + pack Bf + M=A@Wo + pack Mf
// One block per 16 rows (= one j-tile). 96 blocks x 256 threads.
//  A: LN 16 rows (16 thr/row, shfl_xor width-16 reduce) -> sn in LDS (stride 388)
//  B: A,B = sn@W1/W2 + bias; thread (h=t&31, rg=t>>5) does rows 2rg,2rg+1
//  B2: pack Bf fragment for this j-tile (identical layout to old k_packB)
//  C: M[r,d,z] = sum_c A[r,c]*Wo[c,d,z] in 8 chunks (8 d x 128 z x 8 rows)
//     through LDS (reuses sn space), emit bf16 Mf frags (same layout as k_m2)
__global__ __launch_bounds__(256, 1) void k_prep(
    const float* __restrict__ s, const float* __restrict__ g, const float* __restrict__ be,
    const float* __restrict__ W1, const float* __restrict__ pb1,
    const float* __restrict__ W2, const float* __restrict__ pb2,
    const float* __restrict__ Wo,
    unsigned short* __restrict__ Bf, unsigned short* __restrict__ Mf)
{
    const int blk = blockIdx.x;     // 0..95
    const int r0  = blk * 16;
    const int n   = blk / 24;
    const int jt  = blk % 24;
    const int t   = threadIdx.x;

    __shared__ float Afl[16][32];
    __shared__ float Bfl[16][32];
    __shared__ __align__(16) float big[8192];   // 32 KB: sn[16][388], later Msub[8][8][128]

    // ---- Phase A: LayerNorm of 16 rows ----
    {
        const int row = t >> 4, l16 = t & 15;
        const float* srow = s + (size_t)(r0 + row) * CS;
        float x[24];
        #pragma unroll
        for (int k = 0; k < 24; ++k) x[k] = srow[l16 + k * 16];
        float p = 0.f;
        #pragma unroll
        for (int k = 0; k < 24; ++k) p += x[k];
        #pragma unroll
        for (int m = 1; m < 16; m <<= 1) p += __shfl_xor(p, m);
        const float mu = p * (1.0f / CS);
        float q = 0.f;
        #pragma unroll
        for (int k = 0; k < 24; ++k) { float d = x[k] - mu; q += d * d; }
        #pragma unroll
        for (int m = 1; m < 16; m <<= 1) q += __shfl_xor(q, m);
        const float rstd = rsqrtf(q * (1.0f / CS) + EPS);
        #pragma unroll
        for (int k = 0; k < 24; ++k) {
            const int c = l16 + k * 16;
            big[row * 388 + c] = (x[k] - mu) * rstd * g[c] + be[c];
        }
    }
    __syncthreads();

    // ---- Phase B: A,B matvec ----
    {
        const int h = t & 31, rg = t >> 5;   // rows 2rg, 2rg+1
        const float* sn0 = big + (rg * 2) * 388;
        const float* sn1 = sn0 + 388;
        float a0 = 0.f, a1 = 0.f, c0 = 0.f, c1 = 0.f;
        #pragma unroll 4
        for (int c = 0; c < CS; ++c) {
            const float w1 = W1[c * CH + h];
            const float w2 = W2[c * CH + h];
            const float s0 = sn0[c], s1 = sn1[c];
            a0 += s0 * w1; a1 += s1 * w1;
            c0 += s0 * w2; c1 += s1 * w2;
        }
        Afl[rg * 2][h]     = a0 + pb1[h];
        Afl[rg * 2 + 1][h] = a1 + pb1[h];
        Bfl[rg * 2][h]     = c0 + pb2[h];
        Bfl[rg * 2 + 1][h] = c1 + pb2[h];
    }
    __syncthreads();

    // ---- Phase B2: pack Bf for this j-tile ----
    if (t < 64) {
        const int row16 = t & 15, gq = t >> 4;
        u8s o;
        #pragma unroll
        for (int e = 0; e < 8; ++e) o[e] = f2bf(Bfl[row16][gq * 8 + e]);
        *(u8s*)(Bf + (((size_t)(n * 24 + jt)) * 64 + t) * 8) = o;
    }

    // ---- Phase C: M = A@Wo in chunks of (8 d x 128 z) x 8 rows, pack Mf ----
    const int zq = t & 31, dd = t >> 5;
    for (int ch = 0; ch < 4; ++ch) {
        for (int rh = 0; rh < 2; ++rh) {
            __syncthreads();   // prior big readers (sn / Msub pack) are done
            v4f acc[8];
            #pragma unroll
            for (int rr = 0; rr < 8; ++rr) acc[rr] = (v4f)(0.f);
            const float* wop = Wo + (ch * 8 + dd) * 128 + zq * 4;
            #pragma unroll 4
            for (int c = 0; c < CH; ++c) {
                const v4f wv = *(const v4f*)(wop + (size_t)c * 4096);
                #pragma unroll
                for (int rr = 0; rr < 8; ++rr)
                    acc[rr] += Afl[rh * 8 + rr][c] * wv;
            }
            #pragma unroll
            for (int rr = 0; rr < 8; ++rr)
                *(v4f*)(big + rr * 1024 + dd * 128 + zq * 4) = acc[rr];
            __syncthreads();
            #pragma unroll
            for (int i = 0; i < 4; ++i) {
                const int item = t + i * 256;          // 0..1023
                const int c16 = item & 15;
                const int zt  = (item >> 4) & 7;
                const int rr  = item >> 7;
                u8s o;
                #pragma unroll
                for (int e = 0; e < 8; ++e)
                    o[e] = f2bf(big[rr * 1024 + e * 128 + zt * 16 + c16]);
                *(u8s*)(Mf + (((size_t)(r0 + rh * 8 + rr) * 8 + zt) * 64 + ch * 16 + c16) * 8) = o;
            }
        }
    }
}

// ---------------- Kernel 2: out[r,j,z] via MFMA (identical to R11) -----------
// Block = r (256 thr, 4 waves). Wave w: j-tiles {w, w+4, ...} (6) x 8 z-tiles.
// mfma(A=mf[zt], B=af): D row = z-in-tile = (l>>4)*4+e (contiguous in memory),
// col = j-in-tile = l&15 -> one dwordx4 store per (lane, zt).
__global__ __launch_bounds__(256, 4) void k_out(
    const unsigned short* __restrict__ Bf, const unsigned short* __restrict__ Mf,
    const float* __restrict__ bo, float* __restrict__ out)
{
    const int r = blockIdx.x;
    const int t = threadIdx.x;
    const int l = t & 63, w = t >> 6;
    const int g = l >> 4, c16 = l & 15;
    const int n = r / LL;

    s8v mf[8];
    {
        const s8v* Mfr = (const s8v*)(Mf + (size_t)r * 8 * 64 * 8);
        #pragma unroll
        for (int zt = 0; zt < 8; ++zt) mf[zt] = Mfr[zt * 64 + l];
    }
    v4f bov[8];
    #pragma unroll
    for (int zt = 0; zt < 8; ++zt) bov[zt] = *(const v4f*)(bo + zt * 16 + g * 4);

    const s8v* Bfn = (const s8v*)(Bf + (size_t)n * 24 * 64 * 8);
    v4f* outv = (v4f*)(out + (size_t)r * LL * CZ);   // 32 v4f per j-row

    for (int jt = w; jt < 24; jt += 4) {
        const s8v af = Bfn[jt * 64 + l];
        v4f* p = outv + (size_t)(jt * 16 + c16) * 32 + g;
        #pragma unroll
        for (int zt = 0; zt < 8; ++zt) {
            v4f d = __builtin_amdgcn_mfma_f32_16x16x32_bf16(mf[zt], af, (v4f)(0.f), 0, 0, 0);
            p[zt * 4] = d + bov[zt];
        }
    }
}

extern "C" void kernel_launch(void* const* d_in, const int* in_sizes, int n_in,
                              void* d_out, int out_size, void* d_ws, size_t ws_size,
                              hipStream_t stream) {
    const float* s  = (const float*)d_in[0];
    const float* g  = (const float*)d_in[1];
    const float* be = (const float*)d_in[2];
    const float* W1 = (const float*)d_in[3];
    const float* b1 = (const float*)d_in[4];
    const float* W2 = (const float*)d_in[5];
    const float* b2 = (const float*)d_in[6];
    const float* Wo = (const float*)d_in[7];
    const float* bo = (const float*)d_in[8];
    float* out = (float*)d_out;

    // ws layout (bytes): Bf bf16 [0, 98304) | Mf bf16 [98304, 98304+12582912)
    if (ws_size < 98304u + 12582912u) return;  // fail visibly, no UB
    unsigned short* Bf = (unsigned short*)d_ws;
    unsigned short* Mf = (unsigned short*)((char*)d_ws + 98304);

    k_prep<<<96, 256, 0, stream>>>(s, g, be, W1, b1, W2, b2, Wo, Bf, Mf);
    k_out <<<NL, 256, 0, stream>>>(Bf, Mf, bo, out);
}

// Round 13
// 87.860 us; speedup vs baseline: 1.3804x; 1.3804x over previous
//
#include <hip/hip_runtime.h>
#include <hip/hip_bf16.h>

#define CS 384
#define CH 32
#define CZ 128
#define LL 384
#define NL 1536   // N*L
#define EPS 1e-5f

typedef float v2f __attribute__((ext_vector_type(2)));
typedef float v4f __attribute__((ext_vector_type(4)));
typedef short s8v __attribute__((ext_vector_type(8)));          // 8 bf16 (MFMA A/B frag)
typedef unsigned short u8s __attribute__((ext_vector_type(8))); // 8 bf16 bits

static __device__ __forceinline__ unsigned short f2bf(float x) {
    unsigned int b = __float_as_uint(x);
    b += 0x7FFFu + ((b >> 16) & 1u);        // round-to-nearest-even
    return (unsigned short)(b >> 16);
}

// ---------------- Kernel 1: LayerNorm + A = sn@W1+b1, B = sn@W2+b2 ------------
__global__ __launch_bounds__(128) void k_ln_ab(
    const float* __restrict__ s, const float* __restrict__ g, const float* __restrict__ be,
    const float* __restrict__ W1, const float* __restrict__ b1,
    const float* __restrict__ W2, const float* __restrict__ b2,
    float* __restrict__ A, float* __restrict__ B)
{
    const int row = blockIdx.x;
    const int t   = threadIdx.x;
    const int wid = t >> 6, lane = t & 63;
    const float* srow = s + (size_t)row * CS;

    __shared__ float sn[CS];
    __shared__ float red[2];
    __shared__ float part[128];

    float x0 = srow[t], x1 = srow[t + 128], x2 = srow[t + 256];

    float p = x0 + x1 + x2;
    #pragma unroll
    for (int o = 32; o > 0; o >>= 1) p += __shfl_down(p, o);
    if (lane == 0) red[wid] = p;
    __syncthreads();
    const float mu = (red[0] + red[1]) * (1.0f / CS);
    __syncthreads();

    float d0 = x0 - mu, d1 = x1 - mu, d2 = x2 - mu;
    float q = d0 * d0 + d1 * d1 + d2 * d2;
    #pragma unroll
    for (int o = 32; o > 0; o >>= 1) q += __shfl_down(q, o);
    if (lane == 0) red[wid] = q;
    __syncthreads();
    const float var = (red[0] + red[1]) * (1.0f / CS);
    const float rstd = rsqrtf(var + EPS);

    sn[t]       = d0 * rstd * g[t]       + be[t];
    sn[t + 128] = d1 * rstd * g[t + 128] + be[t + 128];
    sn[t + 256] = d2 * rstd * g[t + 256] + be[t + 256];
    __syncthreads();

    {
        const int h    = t & 31;
        const int mat  = (t >> 5) & 1;
        const int half = t >> 6;
        const float* W = mat ? W2 : W1;
        float acc = 0.0f;
        const int c0 = half * (CS / 2);
        #pragma unroll 8
        for (int c = c0; c < c0 + CS / 2; ++c)
            acc += sn[c] * W[c * CH + h];
        part[t] = acc;
    }
    __syncthreads();
    if (t < 64) {
        const int h   = t & 31;
        const int mat = t >> 5;
        const float v = part[t] + part[t + 64] + (mat ? b2[h] : b1[h]);
        (mat ? B : A)[(size_t)row * CH + h] = v;
    }
}

// ---------------- Kernel 1b: pack B into bf16 MFMA fragments -----------------
// Bf[((n*24 + jt)*64 + l)*8 + e] = bf16( B[n, jt*16 + (l&15), (l>>4)*8 + e] )
__global__ __launch_bounds__(64) void k_packB(
    const float* __restrict__ B, unsigned short* __restrict__ Bf)
{
    const int jt = blockIdx.x;      // 0..23
    const int n  = blockIdx.y;      // 0..3
    const int l  = threadIdx.x;     // 0..63
    const int row = jt * 16 + (l & 15);
    const int g   = l >> 4;
    const float* src = B + ((size_t)(n * LL + row)) * CH + g * 8;
    u8s o;
    #pragma unroll
    for (int e = 0; e < 8; ++e) o[e] = f2bf(src[e]);
    *(u8s*)(Bf + (((size_t)(n * 24 + jt)) * 64 + l) * 8) = o;
}

// ---------------- Kernel 2: M = A@Wo in LDS, emit bf16 MFMA frags ------------
// Mf[((r*8 + zt)*64 + l)*8 + e] = bf16( M[r, (l>>4)*8 + e, zt*16 + (l&15)] )
__global__ __launch_bounds__(256, 2) void k_m2(
    const float* __restrict__ A, const float* __restrict__ Wo,
    unsigned short* __restrict__ Mf)
{
    const int t  = threadIdx.x;
    const int r0 = blockIdx.x * 4;
    __shared__ float Al[4][CH];
    __shared__ float Msub[4 * 32 * 128];   // [rr][d][z], 64 KB
    if (t < 128) Al[t >> 5][t & 31] = A[(size_t)(r0 + (t >> 5)) * CH + (t & 31)];
    __syncthreads();

    const v4f* Wo4 = (const v4f*)Wo;       // 1024 v4f per c-row

    #pragma unroll
    for (int it = 0; it < 4; ++it) {
        const int col = t + it * 256;      // col = d*32 + zq
        v4f acc[4];
        #pragma unroll
        for (int r = 0; r < 4; ++r) acc[r] = (v4f)(0.f);
        #pragma unroll 8
        for (int c = 0; c < CH; ++c) {
            const v4f wv = Wo4[(size_t)c * 1024 + col];
            #pragma unroll
            for (int r = 0; r < 4; ++r)
                acc[r] += Al[r][c] * wv;
        }
        #pragma unroll
        for (int r = 0; r < 4; ++r)
            *((v4f*)&Msub[r * 4096 + col * 4]) = acc[r];   // flat = r*4096 + d*128 + zq*4
    }
    __syncthreads();

    #pragma unroll
    for (int i = 0; i < 8; ++i) {
        const int item = t + i * 256;          // 0..2047
        const int l  = item & 63;
        const int zt = (item >> 6) & 7;
        const int rr = item >> 9;
        const int g  = l >> 4;
        const int z  = zt * 16 + (l & 15);
        u8s o;
        #pragma unroll
        for (int e = 0; e < 8; ++e)
            o[e] = f2bf(Msub[rr * 4096 + (g * 8 + e) * 128 + z]);
        *(u8s*)(Mf + (((size_t)(r0 + rr) * 8 + zt) * 64 + l) * 8) = o;
    }
}

// ---------------- Kernel 3: out[r,j,z] via MFMA, loads fully hoisted ---------
// Block = r (256 thr, 4 waves). Wave w: j-tiles {w, w+4, ...} (6) x 8 z-tiles.
// ALL af fragments (6) + mf (8) loaded to VGPRs BEFORE the store loop -> the
// loop contains only MFMA + stores; no vmcnt wait ever covers a store (48
// outstanding stores < 63 cap). D: row = z-in-tile (contig), col = j-in-tile.
__global__ __launch_bounds__(256, 3) void k_out(
    const unsigned short* __restrict__ Bf, const unsigned short* __restrict__ Mf,
    const float* __restrict__ bo, float* __restrict__ out)
{
    const int r = blockIdx.x;
    const int t = threadIdx.x;
    const int l = t & 63, w = t >> 6;
    const int g = l >> 4, c16 = l & 15;
    const int n = r / LL;

    s8v mf[8];
    {
        const s8v* Mfr = (const s8v*)(Mf + (size_t)r * 8 * 64 * 8);
        #pragma unroll
        for (int zt = 0; zt < 8; ++zt) mf[zt] = Mfr[zt * 64 + l];
    }
    s8v af[6];
    {
        const s8v* Bfn = (const s8v*)(Bf + (size_t)n * 24 * 64 * 8);
        #pragma unroll
        for (int i = 0; i < 6; ++i) af[i] = Bfn[(w + i * 4) * 64 + l];
    }
    v4f bov[8];
    #pragma unroll
    for (int zt = 0; zt < 8; ++zt) bov[zt] = *(const v4f*)(bo + zt * 16 + g * 4);

    v4f* outv = (v4f*)(out + (size_t)r * LL * CZ);   // 32 v4f per j-row

    #pragma unroll
    for (int i = 0; i < 6; ++i) {
        const int jt = w + i * 4;
        v4f* p = outv + (size_t)(jt * 16 + c16) * 32 + g;
        #pragma unroll
        for (int zt = 0; zt < 8; ++zt) {
            v4f d = __builtin_amdgcn_mfma_f32_16x16x32_bf16(mf[zt], af[i], (v4f)(0.f), 0, 0, 0);
            p[zt * 4] = d + bov[zt];
        }
    }
}

extern "C" void kernel_launch(void* const* d_in, const int* in_sizes, int n_in,
                              void* d_out, int out_size, void* d_ws, size_t ws_size,
                              hipStream_t stream) {
    const float* s  = (const float*)d_in[0];
    const float* g  = (const float*)d_in[1];
    const float* be = (const float*)d_in[2];
    const float* W1 = (const float*)d_in[3];
    const float* b1 = (const float*)d_in[4];
    const float* W2 = (const float*)d_in[5];
    const float* b2 = (const float*)d_in[6];
    const float* Wo = (const float*)d_in[7];
    const float* bo = (const float*)d_in[8];
    float* out = (float*)d_out;

    // ws layout (bytes): A fp32 [0,196608) | B fp32 [196608,393216)
    //                    | Bf bf16 [393216,491520) | Mf bf16 [491520,+12582912)
    if (ws_size < 491520u + 12582912u) return;  // fail visibly, no UB
    float* A  = (float*)d_ws;
    float* Bm = A + (size_t)NL * CH;
    unsigned short* Bf = (unsigned short*)((char*)d_ws + 393216);
    unsigned short* Mf = (unsigned short*)((char*)d_ws + 491520);

    k_ln_ab<<<NL, 128, 0, stream>>>(s, g, be, W1, b1, W2, b2, A, Bm);
    dim3 gpb(24, 4);
    k_packB<<<gpb, 64, 0, stream>>>(Bm, Bf);
    k_m2  <<<NL / 4, 256, 0, stream>>>(A, Wo, Mf);
    k_out <<<NL, 256, 0, stream>>>(Bf, Mf, bo, out);
}